// Round 7
// baseline (311.803 us; speedup 1.0000x reference)
//
#include <hip/hip_runtime.h>

#define N_NODES 50000
#define N_EDGES 600000
#define C 128
#define STRIPS 3125          // N_NODES / 16
#define N_TASKS 4            // 0 rel(L2) 1 hh0(L1) 2 hh1(L0) 3 loop(L2)
#define MLP_BLOCKS 256       // 1 block/CU; task = blk&3
#define MLP_THREADS 768      // R13: 12 waves/block = 3 waves/SIMD, UNFUSED
#define MAXOVF 16384         // overflow list capacity (expected use: 0)

typedef __bf16 bf16;
typedef __attribute__((ext_vector_type(8))) __bf16 bf16x8;
typedef __attribute__((ext_vector_type(4))) __bf16 bf16x4;
typedef __attribute__((ext_vector_type(2))) __bf16 bf16x2;
typedef __attribute__((ext_vector_type(4))) float f32x4;
typedef __attribute__((ext_vector_type(2))) float f32x2;

struct PtrsV { const void* p[8]; };

// ---------------------------------------------------------------------------
// Dtype detection (verified R2-R6) + cursor zeroing. flags 1=fp32,0=bf16.
// ---------------------------------------------------------------------------
__device__ __forceinline__ int bf16_wild(unsigned short w) {
    int exp = (w >> 7) & 0xFF;
    int mant = w & 0x7F;
    if (exp == 0xFF) return 1;
    if (exp >= 133) return 1;                // |x| >= 64
    if (exp == 0) return mant != 0 ? 1 : 0;  // denormal
    if (exp <= 114) return 1;                // 0 < |x| < 2^-12
    return 0;
}

__global__ void __launch_bounds__(256) detect_zero_kernel(
    const unsigned short* __restrict__ emb,
    const unsigned short* __restrict__ w,
    const unsigned short* __restrict__ b,
    const unsigned short* __restrict__ hc,
    int* __restrict__ flags,
    int* __restrict__ z0, int* __restrict__ z1,   // cursor / deg (may alias)
    int* __restrict__ ovf_cnt)
{
    if (blockIdx.x == 0) {
        int lane = threadIdx.x;
        if (lane >= 64) return;
        int ce = 0, cw = 0, cb = 0, ch = 0;
        for (int j = 0; j < 4; ++j) {
            ce += bf16_wild(emb[lane * 4 + j]);
            cw += bf16_wild(w[lane * 4 + j]);
        }
        for (int j = 0; j < 2; ++j) cb += bf16_wild(b[lane * 2 + j]);
        if (lane < 3) ch = bf16_wild(hc[lane]);
        for (int off = 32; off > 0; off >>= 1) {
            ce += __shfl_down(ce, off);
            cw += __shfl_down(cw, off);
            cb += __shfl_down(cb, off);
            ch += __shfl_down(ch, off);
        }
        if (lane == 0) {
            int wf = (cw >= 16) ? 1 : 0;
            flags[0] = (ce >= 16) ? 1 : 0;
            flags[1] = wf;
            flags[2] = (cb >= 8) ? 1 : 0;
            flags[3] = (ch > 0) ? 1 : wf;
        }
    } else {
        int i = (blockIdx.x - 1) * 256 + threadIdx.x;
        if (i < N_NODES) { z0[i] = 0; z1[i] = 0; }
        if (blockIdx.x == 1 && threadIdx.x == 0) *ovf_cnt = 0;
    }
}

// ---------------------------------------------------------------------------
// Pack weights into MFMA B-fragment order (verified R2-R6).
// Frag index within matrix (as bf16x8): kk*512 + n0*64 + lane.
// Slots 4,5 are the second hh matrix (+16384 elems / +128 bias).
// ---------------------------------------------------------------------------
__global__ void __launch_bounds__(256) pack_kernel(
    PtrsV wmats, PtrsV bvecs, const void* hc_raw,
    const int* __restrict__ flags,
    bf16* __restrict__ pw, float* __restrict__ cbias, float* __restrict__ ccoef)
{
    int tid = blockIdx.x * 256 + threadIdx.x;
    int wf = flags[1], bfl = flags[2], hf = flags[3];
    if (tid < 8 * 16384) {
        int m    = tid >> 14;
        int r    = tid & 16383;
        int j    = r & 7;
        int lane = (r >> 3) & 63;
        int n0   = (r >> 9) & 7;
        int kk   = r >> 12;
        int k = kk * 32 + (lane >> 4) * 8 + j;
        int n = n0 * 16 + (lane & 15);
        int idx = k * C + n + ((m == 4 || m == 5) ? 16384 : 0);
        float v = wf ? ((const float*)wmats.p[m])[idx]
                     : (float)((const bf16*)wmats.p[m])[idx];
        pw[tid] = (bf16)v;
    } else if (tid < 8 * 16384 + 1024) {
        int j = tid - 8 * 16384;
        int m = j >> 7, n = j & 127;
        int idx = n + ((m == 4 || m == 5) ? 128 : 0);
        float v = bfl ? ((const float*)bvecs.p[m])[idx]
                      : (float)((const bf16*)bvecs.p[m])[idx];
        cbias[j] = v;
    } else if (tid < 8 * 16384 + 1024 + 3) {
        int i = tid - (8 * 16384 + 1024);
        float v = hf ? ((const float*)hc_raw)[i]
                     : (float)((const bf16*)hc_raw)[i];
        ccoef[i] = v;
    }
}

// ---------------------------------------------------------------------------
// MLP v9 (R13): R9/R11 structure (measured best 46-48us), UNFUSED, but with
// 12 waves/block (3 waves/SIMD, was 2) -- isolating the waves/SIMD lever
// that R12 confounded with the failed bucket fusion. One task per block,
// task's 64KB packed weights in LDS, waves loop over strips (stride 768)
// with A prefetched one strip ahead. LDS 64KB + 12*4.25KB = 115KB ->
// 1 block/CU. R12 measured 84 VGPR for this body -> no spill at bounds(768,3).
// ---------------------------------------------------------------------------
__global__ __launch_bounds__(MLP_THREADS, 3) void mlp_kernel(
    const void* __restrict__ emb_raw,    // [3][N][C] fp32 or bf16
    const bf16* __restrict__ pw,         // packed weights [8][16384]
    const float* __restrict__ cbias,     // [8][128]
    const float* __restrict__ ccoef,     // [3]
    const int* __restrict__ flags,
    bf16* __restrict__ h,                // [3][N][C], premultiplied by coef
    bf16* __restrict__ hs)               // [N][C] self term (loop MLP)
{
    __shared__ bf16 sW[32768];           // 64 KB: W1 then W2 fragments (this task)
    __shared__ bf16 sH[12][16][136];     // 51 KB: per-wave transpose buffer
    const int tid  = threadIdx.x;
    const int wave = tid >> 6, lane = tid & 63;
    const int task  = blockIdx.x & 3;
    const int bslot = blockIdx.x >> 2;          // 0..63
    const int widx  = bslot * 12 + wave;        // 0..767
    const int lrow = lane & 15, lquad = lane >> 4;
    bf16 (*sh)[136] = sH[wave];

    const int m1_of[4] = {0, 2, 4, 6};
    const int ly_of[4] = {2, 1, 0, 2};
    const int m1 = m1_of[task];
    const float oscale = (task == 0) ? ccoef[0] : (task == 1) ? ccoef[1]
                       : (task == 2) ? ccoef[2] : 1.0f;
    bf16* outp = (task == 3) ? hs : (h + (size_t)task * N_NODES * C);
    const int emb_f32 = flags[0];
    const size_t lbase = (size_t)ly_of[task] * N_NODES * C;

    // ---- stage this task's weights into LDS (64 KB = 4096 x 16B) ----
    {
        const f32x4* src = (const f32x4*)(pw + (size_t)m1 * 16384);
        f32x4* dst = (f32x4*)sW;
        for (int i = tid; i < 4096; i += MLP_THREADS)
            dst[i] = src[i];
    }
    __syncthreads();
    const bf16x8* w1v = (const bf16x8*)sW;      // frag (kk*512 + n0*64 + lane)
    const bf16x8* w2v = w1v + 2048;

    // ---- biases for this lane's columns ----
    float b1f[8], b2f[8];
    #pragma unroll
    for (int n0 = 0; n0 < 8; ++n0) {
        b1f[n0] = cbias[m1 * 128 + n0 * 16 + lrow];
        b2f[n0] = cbias[(m1 + 1) * 128 + n0 * 16 + lrow];
    }

    // ---- strip loop: slot-strided, A prefetched one strip ahead ----
    int s = widx;                               // 0..767
    f32x4 u[8]; bf16x8 araw[4];

    // prologue: issue raw A loads for first strip
    {
        size_t xb = lbase + (size_t)(s * 16 + lrow) * C + lquad * 8;
        if (emb_f32) {
            const float* xf = (const float*)emb_raw + xb;
            #pragma unroll
            for (int kk = 0; kk < 4; ++kk) {
                u[kk * 2]     = *(const f32x4*)(xf + kk * 32);
                u[kk * 2 + 1] = *(const f32x4*)(xf + kk * 32 + 4);
            }
        } else {
            const bf16* x16 = (const bf16*)emb_raw + xb;
            #pragma unroll
            for (int kk = 0; kk < 4; ++kk)
                araw[kk] = *(const bf16x8*)(x16 + kk * 32);
        }
    }

    while (s < STRIPS) {
        const int snext = s + MLP_THREADS / 64 * 64;   // +768

        // convert raw -> af (frees the raw buffers for the prefetch)
        bf16x8 af[4];
        if (emb_f32) {
            #pragma unroll
            for (int kk = 0; kk < 4; ++kk) {
                f32x4 u0 = u[kk * 2], u1 = u[kk * 2 + 1];
                bf16x8 v;
                v[0]=(bf16)u0[0]; v[1]=(bf16)u0[1]; v[2]=(bf16)u0[2]; v[3]=(bf16)u0[3];
                v[4]=(bf16)u1[0]; v[5]=(bf16)u1[1]; v[6]=(bf16)u1[2]; v[7]=(bf16)u1[3];
                af[kk] = v;
            }
        } else {
            #pragma unroll
            for (int kk = 0; kk < 4; ++kk) af[kk] = araw[kk];
        }

        // issue raw A loads for the NEXT strip (in flight during GEMMs)
        if (snext < STRIPS) {
            size_t xb = lbase + (size_t)(snext * 16 + lrow) * C + lquad * 8;
            if (emb_f32) {
                const float* xf = (const float*)emb_raw + xb;
                #pragma unroll
                for (int kk = 0; kk < 4; ++kk) {
                    u[kk * 2]     = *(const f32x4*)(xf + kk * 32);
                    u[kk * 2 + 1] = *(const f32x4*)(xf + kk * 32 + 4);
                }
            } else {
                const bf16* x16 = (const bf16*)emb_raw + xb;
                #pragma unroll
                for (int kk = 0; kk < 4; ++kk)
                    araw[kk] = *(const bf16x8*)(x16 + kk * 32);
            }
        }

        // ---- GEMM1: hidden = relu(X @ W1 + b1) -> sh, B from LDS ----
        #pragma unroll
        for (int n0 = 0; n0 < 8; ++n0) {
            bf16x8 bv0 = w1v[0 * 512 + n0 * 64 + lane];
            bf16x8 bv1 = w1v[1 * 512 + n0 * 64 + lane];
            bf16x8 bv2 = w1v[2 * 512 + n0 * 64 + lane];
            bf16x8 bv3 = w1v[3 * 512 + n0 * 64 + lane];
            int n = n0 * 16 + lrow;
            float bias = b1f[n0];
            f32x4 a4 = {0.f, 0.f, 0.f, 0.f};
            a4 = __builtin_amdgcn_mfma_f32_16x16x32_bf16(af[0], bv0, a4, 0, 0, 0);
            a4 = __builtin_amdgcn_mfma_f32_16x16x32_bf16(af[1], bv1, a4, 0, 0, 0);
            a4 = __builtin_amdgcn_mfma_f32_16x16x32_bf16(af[2], bv2, a4, 0, 0, 0);
            a4 = __builtin_amdgcn_mfma_f32_16x16x32_bf16(af[3], bv3, a4, 0, 0, 0);
            #pragma unroll
            for (int r = 0; r < 4; ++r) {
                float v = a4[r] + bias;
                v = v > 0.f ? v : 0.f;
                sh[lquad * 4 + r][n] = (bf16)v;
            }
        }

        // ---- read GEMM2 A-frags (in-wave LDS RAW, compiler-ordered) ----
        bf16x8 ah[4];
        #pragma unroll
        for (int kk = 0; kk < 4; ++kk)
            ah[kk] = *(const bf16x8*)(&sh[lrow][kk * 32 + lquad * 8]);

        // ---- GEMM2: out = oscale*(hidden @ W2 + b2) -> sh ----
        #pragma unroll
        for (int n0 = 0; n0 < 8; ++n0) {
            bf16x8 bv0 = w2v[0 * 512 + n0 * 64 + lane];
            bf16x8 bv1 = w2v[1 * 512 + n0 * 64 + lane];
            bf16x8 bv2 = w2v[2 * 512 + n0 * 64 + lane];
            bf16x8 bv3 = w2v[3 * 512 + n0 * 64 + lane];
            int n = n0 * 16 + lrow;
            float bias = b2f[n0];
            f32x4 a4 = {0.f, 0.f, 0.f, 0.f};
            a4 = __builtin_amdgcn_mfma_f32_16x16x32_bf16(ah[0], bv0, a4, 0, 0, 0);
            a4 = __builtin_amdgcn_mfma_f32_16x16x32_bf16(ah[1], bv1, a4, 0, 0, 0);
            a4 = __builtin_amdgcn_mfma_f32_16x16x32_bf16(ah[2], bv2, a4, 0, 0, 0);
            a4 = __builtin_amdgcn_mfma_f32_16x16x32_bf16(ah[3], bv3, a4, 0, 0, 0);
            #pragma unroll
            for (int r = 0; r < 4; ++r)
                sh[lquad * 4 + r][n] = (bf16)((a4[r] + bias) * oscale);
        }

        // ---- coalesced store of 16 rows ----
        {
            int row = lane >> 2;
            int cs  = (lane & 3) * 32;
            bf16* dst = outp + (size_t)(s * 16) * C;
            #pragma unroll
            for (int j = 0; j < 4; ++j) {
                bf16x8 v = *(const bf16x8*)(&sh[row][cs + j * 8]);
                *(bf16x8*)(dst + (size_t)row * C + cs + j * 8) = v;
            }
        }

        s = snext;
    }
}

// ---------------------------------------------------------------------------
// R11 bucket path: single edge pass (separate 256-thread kernel; R12 proved
// fusing it into the LDS-heavy mlp kernel is a large regression -- LDS
// reservation kills bucket occupancy and the scatter RMW lands serialized).
// ---------------------------------------------------------------------------
__global__ void __launch_bounds__(256) bucket_kernel(
    const int* __restrict__ erow, const int* __restrict__ ecol,
    const int* __restrict__ ew,
    int* __restrict__ cursor, int* __restrict__ edata,
    int* __restrict__ ovf_cnt, int* __restrict__ ovf, int cap)
{
    int e = blockIdx.x * 256 + threadIdx.x;
    if (e >= N_EDGES) return;
    int dst = erow[e];
    int val = (ecol[e] << 2) | (ew[e] - 1);
    int pos = atomicAdd(&cursor[dst], 1);
    if (pos < cap) {
        edata[(size_t)dst * cap + pos] = val;
    } else {
        int o = atomicAdd(ovf_cnt, 1);
        if (o < MAXOVF) { ovf[2 * o] = dst; ovf[2 * o + 1] = val; }
    }
}

// ---------------------------------------------------------------------------
// CSR fallback path (verified R5/R6) — used only if workspace is too small
// for buckets. hist + 3-phase scan + fill.
// ---------------------------------------------------------------------------
__global__ void __launch_bounds__(256) hist_kernel(
    const int* __restrict__ erow, int* __restrict__ deg)
{
    int e = blockIdx.x * 256 + threadIdx.x;
    if (e >= N_EDGES) return;
    atomicAdd(&deg[erow[e]], 1);
}

__device__ __forceinline__ int wave_incl_scan(int v, int lane) {
    int x = v;
    #pragma unroll
    for (int d = 1; d < 64; d <<= 1) {
        int t = __shfl_up(x, d);
        if (lane >= d) x += t;
    }
    return x;
}

__global__ void __launch_bounds__(256) scanA_kernel(
    const int* __restrict__ deg, int* __restrict__ offsets, int* __restrict__ btot)
{
    __shared__ int swave[4];
    int b = blockIdx.x, tid = threadIdx.x;
    int i = b * 256 + tid;
    int lane = tid & 63, wv = tid >> 6;
    int v = (i < N_NODES) ? deg[i] : 0;
    int x = wave_incl_scan(v, lane);
    if (lane == 63) swave[wv] = x;
    __syncthreads();
    int w0 = swave[0], w1 = swave[1], w2 = swave[2], w3 = swave[3];
    int wp = (wv > 0 ? w0 : 0) + (wv > 1 ? w1 : 0) + (wv > 2 ? w2 : 0);
    if (i < N_NODES) offsets[i] = wp + x - v;
    if (tid == 0) btot[b] = w0 + w1 + w2 + w3;
}

__global__ void __launch_bounds__(256) scanB_kernel(
    const int* __restrict__ btot, int* __restrict__ bbase, int nblk)
{
    __shared__ int swave[4];
    int tid = threadIdx.x;
    int lane = tid & 63, wv = tid >> 6;
    int v = (tid < nblk) ? btot[tid] : 0;
    int x = wave_incl_scan(v, lane);
    if (lane == 63) swave[wv] = x;
    __syncthreads();
    int w0 = swave[0], w1 = swave[1], w2 = swave[2], w3 = swave[3];
    int wp = (wv > 0 ? w0 : 0) + (wv > 1 ? w1 : 0) + (wv > 2 ? w2 : 0);
    if (tid < nblk) bbase[tid] = wp + x - v;
}

__global__ void __launch_bounds__(256) scanC_kernel(
    const int* __restrict__ bbase, int* __restrict__ offsets, int* __restrict__ cursor)
{
    int i = blockIdx.x * 256 + threadIdx.x;
    if (i < N_NODES) {
        int o = offsets[i] + bbase[blockIdx.x];
        offsets[i] = o;
        cursor[i] = o;
    }
    if (i == 0) offsets[N_NODES] = N_EDGES;
}

__global__ void __launch_bounds__(256) fill_kernel(
    const int* __restrict__ erow, const int* __restrict__ ecol,
    const int* __restrict__ ew,
    int* __restrict__ cursor, int* __restrict__ edata)
{
    int e = blockIdx.x * 256 + threadIdx.x;
    if (e >= N_EDGES) return;
    int dst = erow[e];
    int pos = atomicAdd(&cursor[dst], 1);
    edata[pos] = (ecol[e] << 2) | (ew[e] - 1);
}

// ---------------------------------------------------------------------------
// Gather: one wave per node, lane = 2 channels; h coef-premultiplied so the
// inner op is a plain add. cap>0: bucket mode (edata[node*cap], deg=cursor);
// cap==0: CSR mode (offsets segments). 8/4/1 unroll cascade for load ILP.
// ---------------------------------------------------------------------------
__global__ void __launch_bounds__(256) gather_kernel(
    const int* __restrict__ offsets, const int* __restrict__ cursor,
    const int* __restrict__ edata,
    const bf16* __restrict__ h,          // [3][N][C]
    const bf16* __restrict__ hs,         // [N][C]
    void* __restrict__ out,
    const int* __restrict__ flags, int cap)
{
    const int node = blockIdx.x * 4 + (threadIdx.x >> 6);
    if (node >= N_NODES) return;
    const int lane = threadIdx.x & 63;
    const int c = lane * 2;

    bf16x2 sv = *(const bf16x2*)(hs + (size_t)node * C + c);
    float a0 = (float)sv[0], a1 = (float)sv[1];

    int s, e;
    const int* ebase;
    if (cap) {
        int d = cursor[node];
        if (d > cap) d = cap;
        s = 0; e = d;
        ebase = edata + (size_t)node * cap;
    } else {
        s = offsets[node]; e = offsets[node + 1];
        ebase = edata;
    }

    for (int base = s; base < e; base += 64) {
        int idx = base + lane;
        int ed_i = (idx < e) ? ebase[idx] : 0;
        int cnt = e - base; if (cnt > 64) cnt = 64;
        int j = 0;
        for (; j + 8 <= cnt; j += 8) {
            float t0 = 0.f, t1 = 0.f;
            #pragma unroll
            for (int u = 0; u < 8; ++u) {
                int ed = __shfl(ed_i, j + u);
                bf16x2 v = *(const bf16x2*)(h + (size_t)(ed & 3) * (N_NODES * C)
                                              + (size_t)(ed >> 2) * C + c);
                t0 += (float)v[0];
                t1 += (float)v[1];
            }
            a0 += t0; a1 += t1;
        }
        for (; j + 4 <= cnt; j += 4) {
            int e0 = __shfl(ed_i, j);
            int e1 = __shfl(ed_i, j + 1);
            int e2 = __shfl(ed_i, j + 2);
            int e3 = __shfl(ed_i, j + 3);
            bf16x2 v0 = *(const bf16x2*)(h + (size_t)(e0 & 3) * (N_NODES * C) + (size_t)(e0 >> 2) * C + c);
            bf16x2 v1 = *(const bf16x2*)(h + (size_t)(e1 & 3) * (N_NODES * C) + (size_t)(e1 >> 2) * C + c);
            bf16x2 v2 = *(const bf16x2*)(h + (size_t)(e2 & 3) * (N_NODES * C) + (size_t)(e2 >> 2) * C + c);
            bf16x2 v3 = *(const bf16x2*)(h + (size_t)(e3 & 3) * (N_NODES * C) + (size_t)(e3 >> 2) * C + c);
            a0 += (float)v0[0] + (float)v1[0] + (float)v2[0] + (float)v3[0];
            a1 += (float)v0[1] + (float)v1[1] + (float)v2[1] + (float)v3[1];
        }
        for (; j < cnt; ++j) {
            int ed = __shfl(ed_i, j);
            bf16x2 v = *(const bf16x2*)(h + (size_t)(ed & 3) * (N_NODES * C) + (size_t)(ed >> 2) * C + c);
            a0 += (float)v[0];
            a1 += (float)v[1];
        }
    }

    if (flags[0]) {
        f32x2 o; o[0] = a0; o[1] = a1;
        *(f32x2*)((float*)out + (size_t)node * C + c) = o;
    } else {
        bf16x2 o; o[0] = (bf16)a0; o[1] = (bf16)a1;
        *(bf16x2*)((bf16*)out + (size_t)node * C + c) = o;
    }
}

// ---------------------------------------------------------------------------
// Overflow gather: adds overflowed edges into out (runs after gather; stream
// order guarantees no race with gather's plain stores). Expected 0 entries.
// ---------------------------------------------------------------------------
__device__ __forceinline__ float bf2f(unsigned short s) {
    unsigned int u = (unsigned int)s << 16;
    float f; __builtin_memcpy(&f, &u, 4); return f;
}
__device__ __forceinline__ unsigned short f2bf(float f) {
    bf16 b = (bf16)f;
    unsigned short s; __builtin_memcpy(&s, &b, 2); return s;
}

__global__ void __launch_bounds__(256) ovf_kernel(
    const int* __restrict__ ovf_cnt, const int* __restrict__ ovf,
    const bf16* __restrict__ h, void* __restrict__ out,
    const int* __restrict__ flags)
{
    int n = *ovf_cnt; if (n > MAXOVF) n = MAXOVF;
    if (n <= 0) return;
    const int gw = (blockIdx.x * 256 + threadIdx.x) >> 6;
    const int lane = threadIdx.x & 63;
    const int nw = gridDim.x * 4;
    const int c = lane * 2;
    for (int i = gw; i < n; i += nw) {
        int dst = ovf[2 * i], val = ovf[2 * i + 1];
        bf16x2 v = *(const bf16x2*)(h + (size_t)(val & 3) * (N_NODES * C)
                                      + (size_t)(val >> 2) * C + c);
        float v0 = (float)v[0], v1 = (float)v[1];
        if (flags[0]) {
            atomicAdd((float*)out + (size_t)dst * C + c, v0);
            atomicAdd((float*)out + (size_t)dst * C + c + 1, v1);
        } else {
            unsigned int* p = (unsigned int*)((bf16*)out + (size_t)dst * C + c);
            unsigned int old = *p, assumed;
            do {
                assumed = old;
                unsigned short lo = assumed & 0xFFFF, hi = assumed >> 16;
                unsigned int nb = (unsigned int)f2bf(bf2f(lo) + v0)
                                | ((unsigned int)f2bf(bf2f(hi) + v1) << 16);
                old = atomicCAS(p, assumed, nb);
            } while (old != assumed);
        }
    }
}

// ---------------------------------------------------------------------------
extern "C" void kernel_launch(void* const* d_in, const int* in_sizes, int n_in,
                              void* d_out, int out_size, void* d_ws, size_t ws_size,
                              hipStream_t stream) {
    // 0 t | 1 node_embeddings [3,N,C] | 2 edge_index [2,E] | 3 edge_weights [E]
    // 4 loop_W1 5 loop_b1 6 loop_W2 7 loop_b2 | 8 rel_W1 9 rel_b1 10 rel_W2 11 rel_b2
    // 12 hh_W1 [2,C,C] 13 hh_b1 [2,C] 14 hh_W2 [2,C,C] 15 hh_b2 [2,C] | 16 hop_coef [3]
    const void* emb = d_in[1];
    const int*  ei  = (const int*)d_in[2];
    const int*  ew  = (const int*)d_in[3];

    // ---- ws layout (common prefix) ----
    char* base = (char*)d_ws;
    bf16*  h      = (bf16*)base;                          // 38,400,000
    bf16*  hs     = (bf16*)(base + 38400000);             // 12,800,000
    bf16*  pw     = (bf16*)(base + 51200000);             //    262,144
    float* cbias  = (float*)(base + 51462144);            //      4,096
    float* ccoef  = (float*)(base + 51466240);            //         16
    int*   flags  = (int*)(base + 51466256);              //         32 (4 used)
    int*   ovf_cnt= (int*)(base + 51466288);              //         64
    int*   cursor = (int*)(base + 51466752);              //    200,000 -> 51,666,752

    // bucket-mode tail: ovf list + strided edata
    int*   ovf    = (int*)(base + 51666752);              // 131,072 -> 51,797,824
    int*   bedata = (int*)(base + 51797824);
    size_t avail  = ws_size > 51797824 ? ws_size - 51797824 : 0;
    int cap = (int)(avail / (4ull * N_NODES));
    if (cap > 96) cap = 96;
    cap &= ~15;                                           // bucket mode iff cap>=32

    // CSR-mode tail (fallback, same footprint as R6-R10 layout)
    int*   deg    = (int*)(base + 51666752);              //    200,000
    int*   offsets= (int*)(base + 51866752);              //    200,064
    int*   btot   = (int*)(base + 52066816);              //      1,024
    int*   bbase  = (int*)(base + 52067840);              //      1,024
    int*   cedata = (int*)(base + 52068864);              //  2,400,000 -> 54.47MB

    // pack slots: 0 rel_W1, 1 rel_W2, 2 hh_W1[0], 3 hh_W2[0], 4 hh_W1[1], 5 hh_W2[1], 6 loop_W1, 7 loop_W2
    PtrsV wptr;
    wptr.p[0] = d_in[8];   wptr.p[1] = d_in[10];
    wptr.p[2] = d_in[12];  wptr.p[3] = d_in[14];
    wptr.p[4] = d_in[12];  wptr.p[5] = d_in[14];   // +16384 elems inside pack
    wptr.p[6] = d_in[4];   wptr.p[7] = d_in[6];
    PtrsV bptr;
    bptr.p[0] = d_in[9];   bptr.p[1] = d_in[11];
    bptr.p[2] = d_in[13];  bptr.p[3] = d_in[15];
    bptr.p[4] = d_in[13];  bptr.p[5] = d_in[15];   // +128 inside pack
    bptr.p[6] = d_in[5];   bptr.p[7] = d_in[7];

    const int NBLK = (N_NODES + 255) / 256;   // 196
    const int EBLK = (N_EDGES + 255) / 256;
    const int* erow = ei;
    const int* ecol = ei + N_EDGES;

    if (cap >= 32) {
        // ---- bucket path: 6 launches (R11 structure + 12-wave mlp) ----
        detect_zero_kernel<<<1 + NBLK, 256, 0, stream>>>(
            (const unsigned short*)emb, (const unsigned short*)d_in[8],
            (const unsigned short*)d_in[9], (const unsigned short*)d_in[16],
            flags, cursor, cursor, ovf_cnt);

        pack_kernel<<<517, 256, 0, stream>>>(wptr, bptr, d_in[16], flags, pw, cbias, ccoef);

        bucket_kernel<<<EBLK, 256, 0, stream>>>(erow, ecol, ew, cursor, bedata,
                                                ovf_cnt, ovf, cap);

        mlp_kernel<<<MLP_BLOCKS, MLP_THREADS, 0, stream>>>(
            emb, pw, cbias, ccoef, flags, h, hs);

        gather_kernel<<<(N_NODES + 3) / 4, 256, 0, stream>>>(
            cursor, cursor, bedata, h, hs, d_out, flags, cap);

        ovf_kernel<<<32, 256, 0, stream>>>(ovf_cnt, ovf, h, d_out, flags);
    } else {
        // ---- CSR fallback: verified R6-R10 path ----
        detect_zero_kernel<<<1 + NBLK, 256, 0, stream>>>(
            (const unsigned short*)emb, (const unsigned short*)d_in[8],
            (const unsigned short*)d_in[9], (const unsigned short*)d_in[16],
            flags, deg, deg, ovf_cnt);

        pack_kernel<<<517, 256, 0, stream>>>(wptr, bptr, d_in[16], flags, pw, cbias, ccoef);

        hist_kernel<<<EBLK, 256, 0, stream>>>(erow, deg);
        scanA_kernel<<<NBLK, 256, 0, stream>>>(deg, offsets, btot);
        scanB_kernel<<<1, 256, 0, stream>>>(btot, bbase, NBLK);
        scanC_kernel<<<NBLK, 256, 0, stream>>>(bbase, offsets, cursor);
        fill_kernel<<<EBLK, 256, 0, stream>>>(erow, ecol, ew, cursor, cedata);

        mlp_kernel<<<MLP_BLOCKS, MLP_THREADS, 0, stream>>>(
            emb, pw, cbias, ccoef, flags, h, hs);

        gather_kernel<<<(N_NODES + 3) / 4, 256, 0, stream>>>(
            offsets, cursor, cedata, h, hs, d_out, flags, 0);
    }
}

// Round 9
// 245.407 us; speedup vs baseline: 1.2706x; 1.2706x over previous
//
#include <hip/hip_runtime.h>

#define N_NODES 50000
#define N_EDGES 600000
#define C 128
#define STRIPS 3125          // N_NODES / 16
#define N_TASKS 4            // 0 rel(L2) 1 hh0(L1) 2 hh1(L0) 3 loop(L2)
#define MLP_BLOCKS 256       // 1 block/CU; task = blk&3
#define PACK_BLOCKS 517
#define MAXOVF 16384         // overflow list capacity (expected use: 0)

typedef __bf16 bf16;
typedef __attribute__((ext_vector_type(8))) __bf16 bf16x8;
typedef __attribute__((ext_vector_type(4))) __bf16 bf16x4;
typedef __attribute__((ext_vector_type(2))) __bf16 bf16x2;
typedef __attribute__((ext_vector_type(4))) float f32x4;
typedef __attribute__((ext_vector_type(2))) float f32x2;

struct PtrsV { const void* p[8]; };

// ---------------------------------------------------------------------------
// Dtype detection (verified R2-R6) + cursor zeroing. flags 1=fp32,0=bf16.
// ---------------------------------------------------------------------------
__device__ __forceinline__ int bf16_wild(unsigned short w) {
    int exp = (w >> 7) & 0xFF;
    int mant = w & 0x7F;
    if (exp == 0xFF) return 1;
    if (exp >= 133) return 1;                // |x| >= 64
    if (exp == 0) return mant != 0 ? 1 : 0;  // denormal
    if (exp <= 114) return 1;                // 0 < |x| < 2^-12
    return 0;
}

__global__ void __launch_bounds__(256) detect_zero_kernel(
    const unsigned short* __restrict__ emb,
    const unsigned short* __restrict__ w,
    const unsigned short* __restrict__ b,
    const unsigned short* __restrict__ hc,
    int* __restrict__ flags,
    int* __restrict__ z0, int* __restrict__ z1,   // cursor / deg (may alias)
    int* __restrict__ ovf_cnt)
{
    if (blockIdx.x == 0) {
        int lane = threadIdx.x;
        if (lane >= 64) return;
        int ce = 0, cw = 0, cb = 0, ch = 0;
        for (int j = 0; j < 4; ++j) {
            ce += bf16_wild(emb[lane * 4 + j]);
            cw += bf16_wild(w[lane * 4 + j]);
        }
        for (int j = 0; j < 2; ++j) cb += bf16_wild(b[lane * 2 + j]);
        if (lane < 3) ch = bf16_wild(hc[lane]);
        for (int off = 32; off > 0; off >>= 1) {
            ce += __shfl_down(ce, off);
            cw += __shfl_down(cw, off);
            cb += __shfl_down(cb, off);
            ch += __shfl_down(ch, off);
        }
        if (lane == 0) {
            int wf = (cw >= 16) ? 1 : 0;
            flags[0] = (ce >= 16) ? 1 : 0;
            flags[1] = wf;
            flags[2] = (cb >= 8) ? 1 : 0;
            flags[3] = (ch > 0) ? 1 : wf;
        }
    } else {
        int i = (blockIdx.x - 1) * 256 + threadIdx.x;
        if (i < N_NODES) { z0[i] = 0; z1[i] = 0; }
        if (blockIdx.x == 1 && threadIdx.x == 0) *ovf_cnt = 0;
    }
}

// ---------------------------------------------------------------------------
// Merged pack + bucket (R14): blocks 0..516 pack weights into MFMA B-frag
// order (verified R2-R6); blocks 517+ do the bucket edge pass (R11-verified).
// Both depend only on detect (flags / zeroed cursor) -- one launch saved.
// No static LDS here, so bucket blocks run at full occupancy (R12's failure
// mode -- LDS reservation strangling the scatter -- does not apply).
// ---------------------------------------------------------------------------
__global__ void __launch_bounds__(256) pack_bucket_kernel(
    PtrsV wmats, PtrsV bvecs, const void* hc_raw,
    const int* __restrict__ flags,
    bf16* __restrict__ pw, float* __restrict__ cbias, float* __restrict__ ccoef,
    const int* __restrict__ erow, const int* __restrict__ ecol,
    const int* __restrict__ ew,
    int* __restrict__ cursor, int* __restrict__ edata,
    int* __restrict__ ovf_cnt, int* __restrict__ ovf, int cap)
{
    if (blockIdx.x >= PACK_BLOCKS) {
        // ---- bucket half: one edge per thread ----
        int e = (blockIdx.x - PACK_BLOCKS) * 256 + threadIdx.x;
        if (e >= N_EDGES) return;
        int dst = erow[e];
        int val = (ecol[e] << 2) | (ew[e] - 1);
        int pos = atomicAdd(&cursor[dst], 1);
        if (pos < cap) {
            edata[(size_t)dst * cap + pos] = val;
        } else {
            int o = atomicAdd(ovf_cnt, 1);
            if (o < MAXOVF) { ovf[2 * o] = dst; ovf[2 * o + 1] = val; }
        }
        return;
    }

    int tid = blockIdx.x * 256 + threadIdx.x;
    int wf = flags[1], bfl = flags[2], hf = flags[3];
    if (tid < 8 * 16384) {
        int m    = tid >> 14;
        int r    = tid & 16383;
        int j    = r & 7;
        int lane = (r >> 3) & 63;
        int n0   = (r >> 9) & 7;
        int kk   = r >> 12;
        int k = kk * 32 + (lane >> 4) * 8 + j;
        int n = n0 * 16 + (lane & 15);
        int idx = k * C + n + ((m == 4 || m == 5) ? 16384 : 0);
        float v = wf ? ((const float*)wmats.p[m])[idx]
                     : (float)((const bf16*)wmats.p[m])[idx];
        pw[tid] = (bf16)v;
    } else if (tid < 8 * 16384 + 1024) {
        int j = tid - 8 * 16384;
        int m = j >> 7, n = j & 127;
        int idx = n + ((m == 4 || m == 5) ? 128 : 0);
        float v = bfl ? ((const float*)bvecs.p[m])[idx]
                      : (float)((const bf16*)bvecs.p[m])[idx];
        cbias[j] = v;
    } else if (tid < 8 * 16384 + 1024 + 3) {
        int i = tid - (8 * 16384 + 1024);
        float v = hf ? ((const float*)hc_raw)[i]
                     : (float)((const bf16*)hc_raw)[i];
        ccoef[i] = v;
    }
}

// ---------------------------------------------------------------------------
// MLP v10 (R14): exact R9/R11 shape (measured best 46-48us; every deviation
// -- 2-strip R10, 12-wave R12/R13 -- regressed, R13 with an unexplained 3x
// HBM-traffic blowup). One change: the 4-deep MFMA accumulator chain is
// split into two 2-deep chains (c0/c1) summed in the epilogue, halving the
// dependent-latency depth per n0 at the cost of 4 VALU adds. 512 threads,
// 8 waves, task's 64KB weights in LDS, A prefetched one strip ahead.
// LDS 64KB + 8*4.25KB = 100KB -> 1 block/CU.
// ---------------------------------------------------------------------------
__global__ __launch_bounds__(512, 2) void mlp_kernel(
    const void* __restrict__ emb_raw,    // [3][N][C] fp32 or bf16
    const bf16* __restrict__ pw,         // packed weights [8][16384]
    const float* __restrict__ cbias,     // [8][128]
    const float* __restrict__ ccoef,     // [3]
    const int* __restrict__ flags,
    bf16* __restrict__ h,                // [3][N][C], premultiplied by coef
    bf16* __restrict__ hs)               // [N][C] self term (loop MLP)
{
    __shared__ bf16 sW[32768];           // 64 KB: W1 then W2 fragments (this task)
    __shared__ bf16 sH[8][16][136];      // 34.8 KB: per-wave transpose buffer
    const int tid  = threadIdx.x;
    const int wave = tid >> 6, lane = tid & 63;
    const int task  = blockIdx.x & 3;
    const int bslot = blockIdx.x >> 2;          // 0..63
    const int lrow = lane & 15, lquad = lane >> 4;
    bf16 (*sh)[136] = sH[wave];

    const int m1_of[4] = {0, 2, 4, 6};
    const int ly_of[4] = {2, 1, 0, 2};
    const int m1 = m1_of[task];
    const float oscale = (task == 0) ? ccoef[0] : (task == 1) ? ccoef[1]
                       : (task == 2) ? ccoef[2] : 1.0f;
    bf16* outp = (task == 3) ? hs : (h + (size_t)task * N_NODES * C);
    const int emb_f32 = flags[0];
    const size_t lbase = (size_t)ly_of[task] * N_NODES * C;

    // ---- stage this task's weights into LDS (64 KB = 4096 x 16B) ----
    {
        const f32x4* src = (const f32x4*)(pw + (size_t)m1 * 16384);
        f32x4* dst = (f32x4*)sW;
        #pragma unroll
        for (int i = 0; i < 8; ++i)
            dst[i * 512 + tid] = src[i * 512 + tid];
    }
    __syncthreads();
    const bf16x8* w1v = (const bf16x8*)sW;      // frag (kk*512 + n0*64 + lane)
    const bf16x8* w2v = w1v + 2048;

    // ---- biases for this lane's columns ----
    float b1f[8], b2f[8];
    #pragma unroll
    for (int n0 = 0; n0 < 8; ++n0) {
        b1f[n0] = cbias[m1 * 128 + n0 * 16 + lrow];
        b2f[n0] = cbias[(m1 + 1) * 128 + n0 * 16 + lrow];
    }

    // ---- strip loop: slot-strided, A prefetched one strip ahead ----
    int s = bslot * 8 + wave;                   // 0..511
    f32x4 u[8]; bf16x8 araw[4];

    // prologue: issue raw A loads for first strip
    {
        size_t xb = lbase + (size_t)(s * 16 + lrow) * C + lquad * 8;
        if (emb_f32) {
            const float* xf = (const float*)emb_raw + xb;
            #pragma unroll
            for (int kk = 0; kk < 4; ++kk) {
                u[kk * 2]     = *(const f32x4*)(xf + kk * 32);
                u[kk * 2 + 1] = *(const f32x4*)(xf + kk * 32 + 4);
            }
        } else {
            const bf16* x16 = (const bf16*)emb_raw + xb;
            #pragma unroll
            for (int kk = 0; kk < 4; ++kk)
                araw[kk] = *(const bf16x8*)(x16 + kk * 32);
        }
    }

    while (s < STRIPS) {
        const int snext = s + 512;

        // convert raw -> af (frees the raw buffers for the prefetch)
        bf16x8 af[4];
        if (emb_f32) {
            #pragma unroll
            for (int kk = 0; kk < 4; ++kk) {
                f32x4 u0 = u[kk * 2], u1 = u[kk * 2 + 1];
                bf16x8 v;
                v[0]=(bf16)u0[0]; v[1]=(bf16)u0[1]; v[2]=(bf16)u0[2]; v[3]=(bf16)u0[3];
                v[4]=(bf16)u1[0]; v[5]=(bf16)u1[1]; v[6]=(bf16)u1[2]; v[7]=(bf16)u1[3];
                af[kk] = v;
            }
        } else {
            #pragma unroll
            for (int kk = 0; kk < 4; ++kk) af[kk] = araw[kk];
        }

        // issue raw A loads for the NEXT strip (in flight during GEMMs)
        if (snext < STRIPS) {
            size_t xb = lbase + (size_t)(snext * 16 + lrow) * C + lquad * 8;
            if (emb_f32) {
                const float* xf = (const float*)emb_raw + xb;
                #pragma unroll
                for (int kk = 0; kk < 4; ++kk) {
                    u[kk * 2]     = *(const f32x4*)(xf + kk * 32);
                    u[kk * 2 + 1] = *(const f32x4*)(xf + kk * 32 + 4);
                }
            } else {
                const bf16* x16 = (const bf16*)emb_raw + xb;
                #pragma unroll
                for (int kk = 0; kk < 4; ++kk)
                    araw[kk] = *(const bf16x8*)(x16 + kk * 32);
            }
        }

        // ---- GEMM1: hidden = relu(X @ W1 + b1) -> sh, B from LDS ----
        // two 2-deep accumulator chains per n0 (R14: halve dependent depth)
        #pragma unroll
        for (int n0 = 0; n0 < 8; ++n0) {
            bf16x8 bv0 = w1v[0 * 512 + n0 * 64 + lane];
            bf16x8 bv1 = w1v[1 * 512 + n0 * 64 + lane];
            bf16x8 bv2 = w1v[2 * 512 + n0 * 64 + lane];
            bf16x8 bv3 = w1v[3 * 512 + n0 * 64 + lane];
            int n = n0 * 16 + lrow;
            float bias = b1f[n0];
            f32x4 c0 = {0.f, 0.f, 0.f, 0.f};
            f32x4 c1 = {0.f, 0.f, 0.f, 0.f};
            c0 = __builtin_amdgcn_mfma_f32_16x16x32_bf16(af[0], bv0, c0, 0, 0, 0);
            c1 = __builtin_amdgcn_mfma_f32_16x16x32_bf16(af[1], bv1, c1, 0, 0, 0);
            c0 = __builtin_amdgcn_mfma_f32_16x16x32_bf16(af[2], bv2, c0, 0, 0, 0);
            c1 = __builtin_amdgcn_mfma_f32_16x16x32_bf16(af[3], bv3, c1, 0, 0, 0);
            #pragma unroll
            for (int r = 0; r < 4; ++r) {
                float v = c0[r] + c1[r] + bias;
                v = v > 0.f ? v : 0.f;
                sh[lquad * 4 + r][n] = (bf16)v;
            }
        }

        // ---- read GEMM2 A-frags (in-wave LDS RAW, compiler-ordered) ----
        bf16x8 ah[4];
        #pragma unroll
        for (int kk = 0; kk < 4; ++kk)
            ah[kk] = *(const bf16x8*)(&sh[lrow][kk * 32 + lquad * 8]);

        // ---- GEMM2: out = oscale*(hidden @ W2 + b2) -> sh ----
        #pragma unroll
        for (int n0 = 0; n0 < 8; ++n0) {
            bf16x8 bv0 = w2v[0 * 512 + n0 * 64 + lane];
            bf16x8 bv1 = w2v[1 * 512 + n0 * 64 + lane];
            bf16x8 bv2 = w2v[2 * 512 + n0 * 64 + lane];
            bf16x8 bv3 = w2v[3 * 512 + n0 * 64 + lane];
            int n = n0 * 16 + lrow;
            float bias = b2f[n0];
            f32x4 c0 = {0.f, 0.f, 0.f, 0.f};
            f32x4 c1 = {0.f, 0.f, 0.f, 0.f};
            c0 = __builtin_amdgcn_mfma_f32_16x16x32_bf16(ah[0], bv0, c0, 0, 0, 0);
            c1 = __builtin_amdgcn_mfma_f32_16x16x32_bf16(ah[1], bv1, c1, 0, 0, 0);
            c0 = __builtin_amdgcn_mfma_f32_16x16x32_bf16(ah[2], bv2, c0, 0, 0, 0);
            c1 = __builtin_amdgcn_mfma_f32_16x16x32_bf16(ah[3], bv3, c1, 0, 0, 0);
            #pragma unroll
            for (int r = 0; r < 4; ++r)
                sh[lquad * 4 + r][n] = (bf16)((c0[r] + c1[r] + bias) * oscale);
        }

        // ---- coalesced store of 16 rows ----
        {
            int row = lane >> 2;
            int cs  = (lane & 3) * 32;
            bf16* dst = outp + (size_t)(s * 16) * C;
            #pragma unroll
            for (int j = 0; j < 4; ++j) {
                bf16x8 v = *(const bf16x8*)(&sh[row][cs + j * 8]);
                *(bf16x8*)(dst + (size_t)row * C + cs + j * 8) = v;
            }
        }

        s = snext;
    }
}

// ---------------------------------------------------------------------------
// CSR fallback path (verified R5/R6) — used only if workspace is too small
// for buckets. hist + 3-phase scan + fill.
// ---------------------------------------------------------------------------
__global__ void __launch_bounds__(256) hist_kernel(
    const int* __restrict__ erow, int* __restrict__ deg)
{
    int e = blockIdx.x * 256 + threadIdx.x;
    if (e >= N_EDGES) return;
    atomicAdd(&deg[erow[e]], 1);
}

__device__ __forceinline__ int wave_incl_scan(int v, int lane) {
    int x = v;
    #pragma unroll
    for (int d = 1; d < 64; d <<= 1) {
        int t = __shfl_up(x, d);
        if (lane >= d) x += t;
    }
    return x;
}

__global__ void __launch_bounds__(256) scanA_kernel(
    const int* __restrict__ deg, int* __restrict__ offsets, int* __restrict__ btot)
{
    __shared__ int swave[4];
    int b = blockIdx.x, tid = threadIdx.x;
    int i = b * 256 + tid;
    int lane = tid & 63, wv = tid >> 6;
    int v = (i < N_NODES) ? deg[i] : 0;
    int x = wave_incl_scan(v, lane);
    if (lane == 63) swave[wv] = x;
    __syncthreads();
    int w0 = swave[0], w1 = swave[1], w2 = swave[2], w3 = swave[3];
    int wp = (wv > 0 ? w0 : 0) + (wv > 1 ? w1 : 0) + (wv > 2 ? w2 : 0);
    if (i < N_NODES) offsets[i] = wp + x - v;
    if (tid == 0) btot[b] = w0 + w1 + w2 + w3;
}

__global__ void __launch_bounds__(256) scanB_kernel(
    const int* __restrict__ btot, int* __restrict__ bbase, int nblk)
{
    __shared__ int swave[4];
    int tid = threadIdx.x;
    int lane = tid & 63, wv = tid >> 6;
    int v = (tid < nblk) ? btot[tid] : 0;
    int x = wave_incl_scan(v, lane);
    if (lane == 63) swave[wv] = x;
    __syncthreads();
    int w0 = swave[0], w1 = swave[1], w2 = swave[2], w3 = swave[3];
    int wp = (wv > 0 ? w0 : 0) + (wv > 1 ? w1 : 0) + (wv > 2 ? w2 : 0);
    if (tid < nblk) bbase[tid] = wp + x - v;
}

__global__ void __launch_bounds__(256) scanC_kernel(
    const int* __restrict__ bbase, int* __restrict__ offsets, int* __restrict__ cursor)
{
    int i = blockIdx.x * 256 + threadIdx.x;
    if (i < N_NODES) {
        int o = offsets[i] + bbase[blockIdx.x];
        offsets[i] = o;
        cursor[i] = o;
    }
    if (i == 0) offsets[N_NODES] = N_EDGES;
}

__global__ void __launch_bounds__(256) fill_kernel(
    const int* __restrict__ erow, const int* __restrict__ ecol,
    const int* __restrict__ ew,
    int* __restrict__ cursor, int* __restrict__ edata)
{
    int e = blockIdx.x * 256 + threadIdx.x;
    if (e >= N_EDGES) return;
    int dst = erow[e];
    int pos = atomicAdd(&cursor[dst], 1);
    edata[pos] = (ecol[e] << 2) | (ew[e] - 1);
}

// ---------------------------------------------------------------------------
// Gather: one wave per node, lane = 2 channels; h coef-premultiplied so the
// inner op is a plain add. cap>0: bucket mode (edata[node*cap], deg=cursor);
// cap==0: CSR mode (offsets segments). 8/4/1 unroll cascade for load ILP.
// ---------------------------------------------------------------------------
__global__ void __launch_bounds__(256) gather_kernel(
    const int* __restrict__ offsets, const int* __restrict__ cursor,
    const int* __restrict__ edata,
    const bf16* __restrict__ h,          // [3][N][C]
    const bf16* __restrict__ hs,         // [N][C]
    void* __restrict__ out,
    const int* __restrict__ flags, int cap)
{
    const int node = blockIdx.x * 4 + (threadIdx.x >> 6);
    if (node >= N_NODES) return;
    const int lane = threadIdx.x & 63;
    const int c = lane * 2;

    bf16x2 sv = *(const bf16x2*)(hs + (size_t)node * C + c);
    float a0 = (float)sv[0], a1 = (float)sv[1];

    int s, e;
    const int* ebase;
    if (cap) {
        int d = cursor[node];
        if (d > cap) d = cap;
        s = 0; e = d;
        ebase = edata + (size_t)node * cap;
    } else {
        s = offsets[node]; e = offsets[node + 1];
        ebase = edata;
    }

    for (int base = s; base < e; base += 64) {
        int idx = base + lane;
        int ed_i = (idx < e) ? ebase[idx] : 0;
        int cnt = e - base; if (cnt > 64) cnt = 64;
        int j = 0;
        for (; j + 8 <= cnt; j += 8) {
            float t0 = 0.f, t1 = 0.f;
            #pragma unroll
            for (int u = 0; u < 8; ++u) {
                int ed = __shfl(ed_i, j + u);
                bf16x2 v = *(const bf16x2*)(h + (size_t)(ed & 3) * (N_NODES * C)
                                              + (size_t)(ed >> 2) * C + c);
                t0 += (float)v[0];
                t1 += (float)v[1];
            }
            a0 += t0; a1 += t1;
        }
        for (; j + 4 <= cnt; j += 4) {
            int e0 = __shfl(ed_i, j);
            int e1 = __shfl(ed_i, j + 1);
            int e2 = __shfl(ed_i, j + 2);
            int e3 = __shfl(ed_i, j + 3);
            bf16x2 v0 = *(const bf16x2*)(h + (size_t)(e0 & 3) * (N_NODES * C) + (size_t)(e0 >> 2) * C + c);
            bf16x2 v1 = *(const bf16x2*)(h + (size_t)(e1 & 3) * (N_NODES * C) + (size_t)(e1 >> 2) * C + c);
            bf16x2 v2 = *(const bf16x2*)(h + (size_t)(e2 & 3) * (N_NODES * C) + (size_t)(e2 >> 2) * C + c);
            bf16x2 v3 = *(const bf16x2*)(h + (size_t)(e3 & 3) * (N_NODES * C) + (size_t)(e3 >> 2) * C + c);
            a0 += (float)v0[0] + (float)v1[0] + (float)v2[0] + (float)v3[0];
            a1 += (float)v0[1] + (float)v1[1] + (float)v2[1] + (float)v3[1];
        }
        for (; j < cnt; ++j) {
            int ed = __shfl(ed_i, j);
            bf16x2 v = *(const bf16x2*)(h + (size_t)(ed & 3) * (N_NODES * C) + (size_t)(ed >> 2) * C + c);
            a0 += (float)v[0];
            a1 += (float)v[1];
        }
    }

    if (flags[0]) {
        f32x2 o; o[0] = a0; o[1] = a1;
        *(f32x2*)((float*)out + (size_t)node * C + c) = o;
    } else {
        bf16x2 o; o[0] = (bf16)a0; o[1] = (bf16)a1;
        *(bf16x2*)((bf16*)out + (size_t)node * C + c) = o;
    }
}

// ---------------------------------------------------------------------------
// Overflow gather: adds overflowed edges into out (runs after gather; stream
// order guarantees no race with gather's plain stores). Expected 0 entries.
// ---------------------------------------------------------------------------
__device__ __forceinline__ float bf2f(unsigned short s) {
    unsigned int u = (unsigned int)s << 16;
    float f; __builtin_memcpy(&f, &u, 4); return f;
}
__device__ __forceinline__ unsigned short f2bf(float f) {
    bf16 b = (bf16)f;
    unsigned short s; __builtin_memcpy(&s, &b, 2); return s;
}

__global__ void __launch_bounds__(256) ovf_kernel(
    const int* __restrict__ ovf_cnt, const int* __restrict__ ovf,
    const bf16* __restrict__ h, void* __restrict__ out,
    const int* __restrict__ flags)
{
    int n = *ovf_cnt; if (n > MAXOVF) n = MAXOVF;
    if (n <= 0) return;
    const int gw = (blockIdx.x * 256 + threadIdx.x) >> 6;
    const int lane = threadIdx.x & 63;
    const int nw = gridDim.x * 4;
    const int c = lane * 2;
    for (int i = gw; i < n; i += nw) {
        int dst = ovf[2 * i], val = ovf[2 * i + 1];
        bf16x2 v = *(const bf16x2*)(h + (size_t)(val & 3) * (N_NODES * C)
                                      + (size_t)(val >> 2) * C + c);
        float v0 = (float)v[0], v1 = (float)v[1];
        if (flags[0]) {
            atomicAdd((float*)out + (size_t)dst * C + c, v0);
            atomicAdd((float*)out + (size_t)dst * C + c + 1, v1);
        } else {
            unsigned int* p = (unsigned int*)((bf16*)out + (size_t)dst * C + c);
            unsigned int old = *p, assumed;
            do {
                assumed = old;
                unsigned short lo = assumed & 0xFFFF, hi = assumed >> 16;
                unsigned int nb = (unsigned int)f2bf(bf2f(lo) + v0)
                                | ((unsigned int)f2bf(bf2f(hi) + v1) << 16);
                old = atomicCAS(p, assumed, nb);
            } while (old != assumed);
        }
    }
}

// ---------------------------------------------------------------------------
extern "C" void kernel_launch(void* const* d_in, const int* in_sizes, int n_in,
                              void* d_out, int out_size, void* d_ws, size_t ws_size,
                              hipStream_t stream) {
    // 0 t | 1 node_embeddings [3,N,C] | 2 edge_index [2,E] | 3 edge_weights [E]
    // 4 loop_W1 5 loop_b1 6 loop_W2 7 loop_b2 | 8 rel_W1 9 rel_b1 10 rel_W2 11 rel_b2
    // 12 hh_W1 [2,C,C] 13 hh_b1 [2,C] 14 hh_W2 [2,C,C] 15 hh_b2 [2,C] | 16 hop_coef [3]
    const void* emb = d_in[1];
    const int*  ei  = (const int*)d_in[2];
    const int*  ew  = (const int*)d_in[3];

    // ---- ws layout (common prefix) ----
    char* base = (char*)d_ws;
    bf16*  h      = (bf16*)base;                          // 38,400,000
    bf16*  hs     = (bf16*)(base + 38400000);             // 12,800,000
    bf16*  pw     = (bf16*)(base + 51200000);             //    262,144
    float* cbias  = (float*)(base + 51462144);            //      4,096
    float* ccoef  = (float*)(base + 51466240);            //         16
    int*   flags  = (int*)(base + 51466256);              //         32 (4 used)
    int*   ovf_cnt= (int*)(base + 51466288);              //         64
    int*   cursor = (int*)(base + 51466752);              //    200,000 -> 51,666,752

    // bucket-mode tail: ovf list + strided edata
    int*   ovf    = (int*)(base + 51666752);              // 131,072 -> 51,797,824
    int*   bedata = (int*)(base + 51797824);
    size_t avail  = ws_size > 51797824 ? ws_size - 51797824 : 0;
    int cap = (int)(avail / (4ull * N_NODES));
    if (cap > 96) cap = 96;
    cap &= ~15;                                           // bucket mode iff cap>=32

    // CSR-mode tail (fallback, same footprint as R6-R10 layout)
    int*   deg    = (int*)(base + 51666752);              //    200,000
    int*   offsets= (int*)(base + 51866752);              //    200,064
    int*   btot   = (int*)(base + 52066816);              //      1,024
    int*   bbase  = (int*)(base + 52067840);              //      1,024
    int*   cedata = (int*)(base + 52068864);              //  2,400,000 -> 54.47MB

    // pack slots: 0 rel_W1, 1 rel_W2, 2 hh_W1[0], 3 hh_W2[0], 4 hh_W1[1], 5 hh_W2[1], 6 loop_W1, 7 loop_W2
    PtrsV wptr;
    wptr.p[0] = d_in[8];   wptr.p[1] = d_in[10];
    wptr.p[2] = d_in[12];  wptr.p[3] = d_in[14];
    wptr.p[4] = d_in[12];  wptr.p[5] = d_in[14];   // +16384 elems inside pack
    wptr.p[6] = d_in[4];   wptr.p[7] = d_in[6];
    PtrsV bptr;
    bptr.p[0] = d_in[9];   bptr.p[1] = d_in[11];
    bptr.p[2] = d_in[13];  bptr.p[3] = d_in[15];
    bptr.p[4] = d_in[13];  bptr.p[5] = d_in[15];   // +128 inside pack
    bptr.p[6] = d_in[5];   bptr.p[7] = d_in[7];

    const int NBLK = (N_NODES + 255) / 256;   // 196
    const int EBLK = (N_EDGES + 255) / 256;   // 2344
    const int* erow = ei;
    const int* ecol = ei + N_EDGES;

    if (cap >= 32) {
        // ---- bucket path: 5 launches ----
        detect_zero_kernel<<<1 + NBLK, 256, 0, stream>>>(
            (const unsigned short*)emb, (const unsigned short*)d_in[8],
            (const unsigned short*)d_in[9], (const unsigned short*)d_in[16],
            flags, cursor, cursor, ovf_cnt);

        pack_bucket_kernel<<<PACK_BLOCKS + EBLK, 256, 0, stream>>>(
            wptr, bptr, d_in[16], flags, pw, cbias, ccoef,
            erow, ecol, ew, cursor, bedata, ovf_cnt, ovf, cap);

        mlp_kernel<<<MLP_BLOCKS, 512, 0, stream>>>(
            emb, pw, cbias, ccoef, flags, h, hs);

        gather_kernel<<<(N_NODES + 3) / 4, 256, 0, stream>>>(
            cursor, cursor, bedata, h, hs, d_out, flags, cap);

        ovf_kernel<<<32, 256, 0, stream>>>(ovf_cnt, ovf, h, d_out, flags);
    } else {
        // ---- CSR fallback: verified R6-R10 path ----
        detect_zero_kernel<<<1 + NBLK, 256, 0, stream>>>(
            (const unsigned short*)emb, (const unsigned short*)d_in[8],
            (const unsigned short*)d_in[9], (const unsigned short*)d_in[16],
            flags, deg, deg, ovf_cnt);

        pack_bucket_kernel<<<PACK_BLOCKS, 256, 0, stream>>>(
            wptr, bptr, d_in[16], flags, pw, cbias, ccoef,
            erow, ecol, ew, cursor, cedata, ovf_cnt, ovf, 0);

        hist_kernel<<<EBLK, 256, 0, stream>>>(erow, deg);
        scanA_kernel<<<NBLK, 256, 0, stream>>>(deg, offsets, btot);
        scanB_kernel<<<1, 256, 0, stream>>>(btot, bbase, NBLK);
        scanC_kernel<<<NBLK, 256, 0, stream>>>(bbase, offsets, cursor);
        fill_kernel<<<EBLK, 256, 0, stream>>>(erow, ecol, ew, cursor, cedata);

        mlp_kernel<<<MLP_BLOCKS, 512, 0, stream>>>(
            emb, pw, cbias, ccoef, flags, h, hs);

        gather_kernel<<<(N_NODES + 3) / 4, 256, 0, stream>>>(
            offsets, cursor, cedata, h, hs, d_out, flags, 0);
    }
}